// Round 8
// baseline (1053.979 us; speedup 1.0000x reference)
//
#include <hip/hip_runtime.h>

// MoE: B=4,S=2048,D=1024,E=8,H=4096,K=2.  T = B*S = 8192 tokens.
// R8: BK=32, 3 LDS buffers (3x32KB), 2-iteration-deep counted-vmcnt pipeline:
// iter-entry wait = vmcnt(4) (iter s loads retire, s+1 stays in flight),
// per-iter 2 phases of {ds_read | issue 2 gl_lds for s+2 | barrier | 16 MFMA}.
// Swizzle swz(r,kc16)=(r*64)^kc16^(((r>>1)&7)<<4) (R7-verified conflict-free).
// ws usage ~407 MB.

#define T_TOK 8192
#define DDIM 1024
#define EEXP 8
#define HDIM 4096
#define RMAX 18432   // T*K + E*256 padding

typedef short short8 __attribute__((ext_vector_type(8)));
typedef float f32x4 __attribute__((ext_vector_type(4)));
typedef unsigned short ushort4v __attribute__((ext_vector_type(4)));
typedef unsigned int u32;

__device__ __forceinline__ unsigned short f2bf(float f) {
  unsigned u = __builtin_bit_cast(unsigned, f);
  return (unsigned short)((u + 0x7FFFu + ((u >> 16) & 1u)) >> 16);
}
__device__ __forceinline__ float bf2f(unsigned short b) {
  unsigned u = ((unsigned)b) << 16;
  return __builtin_bit_cast(float, u);
}
__device__ __forceinline__ void gl_lds16(const void* g, void* l) {
  __builtin_amdgcn_global_load_lds((const u32 __attribute__((address_space(1)))*)g,
                                   (u32 __attribute__((address_space(3)))*)l, 16, 0, 0);
}
#define BAR() asm volatile("s_barrier" ::: "memory")
#define VW4() asm volatile("s_waitcnt vmcnt(4)" ::: "memory")
#define VW0() asm volatile("s_waitcnt vmcnt(0)" ::: "memory")
#define MFMA_BF16 __builtin_amdgcn_mfma_f32_16x16x32_bf16

// in-tile swizzle for 64B rows (32 bf16), 16B chunks (R7-verified):
__device__ __forceinline__ int swz(int r, int kc16) {
  return (r * 64) ^ kc16 ^ (((r >> 1) & 7) << 4);
}
// staging inverse map: dest chunk c -> (row r, k-chunk kc)  (R7-verified)
#define INV_MAP(c, r, kc) { int _h = (c) >> 3;                                   \
    r = 2 * _h + ((((c) >> 2) ^ (_h >> 2)) & 1);                                 \
    kc = ((c) & 3) ^ (_h & 3); }

// ---- weights: f32 [E][K][N] -> bf16 swizzled 8KB tiles, all 3 fused --------
__global__ void k_convert_all(const float* __restrict__ w1, const float* __restrict__ w2,
                              const float* __restrict__ wp,
                              unsigned short* __restrict__ w1s, unsigned short* __restrict__ w2s,
                              unsigned short* __restrict__ wps) {
  __shared__ float lbuf[32][130];
  int bid = blockIdx.x;                 // 0..24575
  int seg = bid >> 13;                  // 0,1,2
  int t = bid & 8191;
  const float* src; unsigned short* dst; int N, K, ct, kt, e;
  e = t >> 10;
  if (seg < 2) {
    src = (seg == 0) ? w1 : w2; dst = (seg == 0) ? w1s : w2s;
    N = HDIM; K = DDIM; ct = (t >> 5) & 31; kt = t & 31;
  } else {
    src = wp; dst = wps;
    N = DDIM; K = HDIM; ct = (t >> 7) & 7; kt = t & 127;
  }
  int tid = threadIdx.x;
  const float* s = src + (size_t)e * K * N + (size_t)(kt * 32) * N + ct * 128;
#pragma unroll
  for (int q = 0; q < 4; q++) {
    int idx = q * 256 + tid;
    int row = idx >> 5, c4 = (idx & 31) * 4;
    float4 v = *(const float4*)(s + (size_t)row * N + c4);
    lbuf[row][c4 + 0] = v.x; lbuf[row][c4 + 1] = v.y;
    lbuf[row][c4 + 2] = v.z; lbuf[row][c4 + 3] = v.w;
  }
  __syncthreads();
  char* dt = (char*)dst + ((size_t)(e * (N / 128) + ct) * (K / 32) + kt) * 8192;
#pragma unroll
  for (int q = 0; q < 2; q++) {
    int idx = q * 256 + tid;
    int n = idx >> 2, kc = idx & 3;
    short8 o;
#pragma unroll
    for (int j = 0; j < 8; j++) o[j] = (short)f2bf(lbuf[kc * 8 + j][n]);
    *(short8*)(dt + swz(n, kc * 16)) = o;
  }
}

// ---- init ------------------------------------------------------------------
__global__ void k_init(int* __restrict__ rowtok, int* __restrict__ counts, int* __restrict__ cursor) {
  int i = blockIdx.x * 256 + threadIdx.x;
  if (i < RMAX) rowtok[i] = 0;
  if (i < EEXP) { counts[i] = 0; cursor[i] = 0; }
}

// ---- gating (+ fused x->bf16) ----------------------------------------------
__launch_bounds__(256)
__global__ void k_gate(const float* __restrict__ x, const float* __restrict__ gw,
                       const float* __restrict__ nwt, const float* __restrict__ noi,
                       int* __restrict__ tki, float* __restrict__ tkp,
                       int* __restrict__ counts, unsigned short* __restrict__ xb) {
  __shared__ float gwT[8][1024];
  int tid = threadIdx.x;
#pragma unroll
  for (int q = 0; q < 32; q++) {
    int flat = q * 256 + tid;
    gwT[flat & 7][flat >> 3] = gw[flat];
  }
  __syncthreads();
  int wave = tid >> 6, l = tid & 63;
  int t = blockIdx.x * 4 + wave;
  float acc[8] = {0.f, 0.f, 0.f, 0.f, 0.f, 0.f, 0.f, 0.f};
  const float4* xr = (const float4*)(x + (size_t)t * DDIM);
#pragma unroll
  for (int i = 0; i < 4; i++) {
    float4 xv = xr[l + i * 64];
    int d0 = (l + i * 64) * 4;
    ushort4v o;
    o.x = f2bf(xv.x); o.y = f2bf(xv.y); o.z = f2bf(xv.z); o.w = f2bf(xv.w);
    *(ushort4v*)(xb + (size_t)t * DDIM + d0) = o;
#pragma unroll
    for (int e = 0; e < 8; e++) {
      float4 gv = *(const float4*)&gwT[e][d0];
      acc[e] += xv.x * gv.x + xv.y * gv.y + xv.z * gv.z + xv.w * gv.w;
    }
  }
#pragma unroll
  for (int s = 1; s < 64; s <<= 1) {
#pragma unroll
    for (int e = 0; e < 8; e++) acc[e] += __shfl_xor(acc[e], s, 64);
  }
  if (l == 0) {
    float nl[8];
#pragma unroll
    for (int e = 0; e < 8; e++) nl[e] = acc[e] + noi[t * 8 + e] * nwt[e];
    int i0 = 0; float v0 = nl[0];
#pragma unroll
    for (int e = 1; e < 8; e++) if (nl[e] > v0) { v0 = nl[e]; i0 = e; }
    int i1 = -1; float v1 = -3.4e38f;
#pragma unroll
    for (int e = 0; e < 8; e++) if (e != i0 && nl[e] > v1) { v1 = nl[e]; i1 = e; }
    float ex = __expf(v1 - v0);
    float p0 = 1.f / (1.f + ex);
    float p1 = ex * p0;
    tki[2 * t] = i0; tki[2 * t + 1] = i1;
    tkp[2 * t] = p0; tkp[2 * t + 1] = p1;
    atomicAdd(&counts[i0], 1);
    atomicAdd(&counts[i1], 1);
  }
}

// ---- prefix (pad to 256-row tiles) -----------------------------------------
__global__ void k_prefix(const int* __restrict__ counts, int* __restrict__ basep) {
  if (threadIdx.x == 0) {
    int b = 0;
    for (int e = 0; e < EEXP; e++) { basep[e] = b; b += (counts[e] + 255) & ~255; }
  }
}

// ---- scatter ---------------------------------------------------------------
__global__ void k_scatter(const int* __restrict__ tki, const int* __restrict__ basep,
                          int* __restrict__ cursor, int* __restrict__ rowtok,
                          int* __restrict__ t2r) {
  int t = blockIdx.x * 256 + threadIdx.x;
  if (t >= T_TOK) return;
#pragma unroll
  for (int k = 0; k < 2; k++) {
    int e = tki[2 * t + k];
    int pos = atomicAdd(&cursor[e], 1);
    int row = basep[e] + pos;
    rowtok[row] = t;
    t2r[2 * t + k] = row;
  }
}

// ---- GEMM1: BM=256, dual-B 128 cols, BK=32, 3 bufs, 2-deep counted ---------
__launch_bounds__(512, 1)
__global__ void k_gemm1(const unsigned short* __restrict__ xb,
                        const unsigned short* __restrict__ w1s, const unsigned short* __restrict__ w2s,
                        const float* __restrict__ b1g, const float* __restrict__ b2g,
                        const int* __restrict__ counts, const int* __restrict__ basep,
                        const int* __restrict__ rowtok,
                        unsigned short* __restrict__ hout) {
  int e = blockIdx.y >> 6;
  int rt = blockIdx.y & 63;
  int cnt = counts[e];
  if (rt >= ((cnt + 255) >> 8)) return;
  int ct = blockIdx.x;              // 0..31 over H
  int row0 = basep[e] + rt * 256;
  int col0 = ct * 128;

  __shared__ char smem[98304];      // 3 bufs x (A 16KB | B1 8KB | B2 8KB)
  __shared__ int s_tok[256];
  __shared__ float s_b1[128], s_b2[128];

  int tid = threadIdx.x;
  if (tid < 256) s_tok[tid] = rowtok[row0 + tid];
  if (tid < 128) {
    s_b1[tid] = b1g[e * HDIM + col0 + tid];
    s_b2[tid] = b2g[e * HDIM + col0 + tid];
  }
  __syncthreads();

  int wave = tid >> 6, l = tid & 63;
  int wm = wave >> 2, wn = wave & 3;          // 2M x 4N
  int g = l >> 4, ln = l & 15;

  // A staging: chunk c0 = tid (rows 0-127), c1 = 512+tid (rows 128-255)
  int c0 = tid, c1 = 512 + tid;
  int r0, kc0, r1, kc1;
  INV_MAP(c0, r0, kc0) INV_MAP(c1, r1, kc1)
  size_t a_src0 = (size_t)s_tok[r0] * 2048 + (size_t)(kc0 * 16);
  size_t a_src1 = (size_t)s_tok[r1] * 2048 + (size_t)(kc1 * 16);
  int a_dst0 = c0 * 16, a_dst1 = c1 * 16;

  int a_rd[8];
#pragma unroll
  for (int m = 0; m < 8; m++) {
    int r = wm * 128 + m * 16 + ln;
    a_rd[m] = swz(r, g * 16);
  }
  int b_rd[2];
#pragma unroll
  for (int n = 0; n < 2; n++) {
    int r = wn * 32 + n * 16 + ln;
    b_rd[n] = swz(r, g * 16);
  }

  f32x4 zero = {0.f, 0.f, 0.f, 0.f};
  f32x4 acc_a[8][2], acc_b[8][2];
#pragma unroll
  for (int m = 0; m < 8; m++)
#pragma unroll
    for (int n = 0; n < 2; n++) { acc_a[m][n] = zero; acc_b[m][n] = zero; }

  const char* xbb = (const char*)xb;
  const char* w1t = (const char*)w1s + (size_t)(e * 32 + ct) * 32 * 8192;
  const char* w2t = (const char*)w2s + (size_t)(e * 32 + ct) * 32 * 8192;

  // prologue: iters 0,1 in phase order {Ah0,B1},{Ah1,B2}
#pragma unroll
  for (int s = 0; s < 2; s++) {
    char* nb = smem + s * 32768;
    gl_lds16(xbb + a_src0 + (size_t)s * 64, nb + a_dst0);
    gl_lds16(w1t + (size_t)s * 8192 + tid * 16, nb + 16384 + tid * 16);
    gl_lds16(xbb + a_src1 + (size_t)s * 64, nb + a_dst1);
    gl_lds16(w2t + (size_t)s * 8192 + tid * 16, nb + 24576 + tid * 16);
  }

  const int NT = 32;                // K=1024 / 32
  int bc = 0;
  for (int s = 0; s < NT; ++s) {
    if (s < NT - 1) VW4(); else VW0();
    BAR();
    char* buf = smem + bc * 32768;
    int nbi = bc + 2; if (nbi >= 3) nbi -= 3;
    char* nbuf = smem + nbi * 32768;
    bool pf = (s < NT - 2);
    // ---- phase 1: m0-3 ----
    short8 af0, af1, af2, af3, b1f0, b1f1, b2f0, b2f1;
    af0 = *(const short8*)(buf + a_rd[0]);
    af1 = *(const short8*)(buf + a_rd[1]);
    af2 = *(const short8*)(buf + a_rd[2]);
    af3 = *(const short8*)(buf + a_rd[3]);
    b1f0 = *(const short8*)(buf + 16384 + b_rd[0]);
    b1f1 = *(const short8*)(buf + 16384 + b_rd[1]);
    b2f0 = *(const short8*)(buf + 24576 + b_rd[0]);
    b2f1 = *(const short8*)(buf + 24576 + b_rd[1]);
    if (pf) {
      gl_lds16(xbb + a_src0 + (size_t)(s + 2) * 64, nbuf + a_dst0);
      gl_lds16(w1t + (size_t)(s + 2) * 8192 + tid * 16, nbuf + 16384 + tid * 16);
    }
    BAR();
    __builtin_amdgcn_s_setprio(1);
    acc_a[0][0] = MFMA_BF16(af0, b1f0, acc_a[0][0], 0, 0, 0);
    acc_a[0][1] = MFMA_BF16(af0, b1f1, acc_a[0][1], 0, 0, 0);
    acc_b[0][0] = MFMA_BF16(af0, b2f0, acc_b[0][0], 0, 0, 0);
    acc_b[0][1] = MFMA_BF16(af0, b2f1, acc_b[0][1], 0, 0, 0);
    acc_a[1][0] = MFMA_BF16(af1, b1f0, acc_a[1][0], 0, 0, 0);
    acc_a[1][1] = MFMA_BF16(af1, b1f1, acc_a[1][1], 0, 0, 0);
    acc_b[1][0] = MFMA_BF16(af1, b2f0, acc_b[1][0], 0, 0, 0);
    acc_b[1][1] = MFMA_BF16(af1, b2f1, acc_b[1][1], 0, 0, 0);
    acc_a[2][0] = MFMA_BF16(af2, b1f0, acc_a[2][0], 0, 0, 0);
    acc_a[2][1] = MFMA_BF16(af2, b1f1, acc_a[2][1], 0, 0, 0);
    acc_b[2][0] = MFMA_BF16(af2, b2f0, acc_b[2][0], 0, 0, 0);
    acc_b[2][1] = MFMA_BF16(af2, b2f1, acc_b[2][1], 0, 0, 0);
    acc_a[3][0] = MFMA_BF16(af3, b1f0, acc_a[3][0], 0, 0, 0);
    acc_a[3][1] = MFMA_BF16(af3, b1f1, acc_a[3][1], 0, 0, 0);
    acc_b[3][0] = MFMA_BF16(af3, b2f0, acc_b[3][0], 0, 0, 0);
    acc_b[3][1] = MFMA_BF16(af3, b2f1, acc_b[3][1], 0, 0, 0);
    __builtin_amdgcn_s_setprio(0);
    BAR();
    // ---- phase 2: m4-7 (B frags reused) ----
    af0 = *(const short8*)(buf + a_rd[4]);
    af1 = *(const short8*)(buf + a_rd[5]);
    af2 = *(const short8*)(buf + a_rd[6]);
    af3 = *(const short8*)(buf + a_rd[7]);
    if (pf) {
      gl_lds16(xbb + a_src1 + (size_t)(s + 2) * 64, nbuf + a_dst1);
      gl_lds16(w2t + (size_t)(s + 2) * 8192 + tid * 16, nbuf + 24576 + tid * 16);
    }
    BAR();
    __builtin_amdgcn_s_setprio(1);
    acc_a[4][0] = MFMA_BF16(af0, b1f0, acc_a[4][0], 0, 0, 0);
    acc_a[4][1] = MFMA_BF16(af0, b1f1, acc_a[4][1], 0, 0, 0);
    acc_b[4][0] = MFMA_BF16(af0, b2f0, acc_b[4][0], 0, 0, 0);
    acc_b[4][1] = MFMA_BF16(af0, b2f1, acc_b[4][1], 0, 0, 0);
    acc_a[5][0] = MFMA_BF16(af1, b1f0, acc_a[5][0], 0, 0, 0);
    acc_a[5][1] = MFMA_BF16(af1, b1f1, acc_a[5][1], 0, 0, 0);
    acc_b[5][0] = MFMA_BF16(af1, b2f0, acc_b[5][0], 0, 0, 0);
    acc_b[5][1] = MFMA_BF16(af1, b2f1, acc_b[5][1], 0, 0, 0);
    acc_a[6][0] = MFMA_BF16(af2, b1f0, acc_a[6][0], 0, 0, 0);
    acc_a[6][1] = MFMA_BF16(af2, b1f1, acc_a[6][1], 0, 0, 0);
    acc_b[6][0] = MFMA_BF16(af2, b2f0, acc_b[6][0], 0, 0, 0);
    acc_b[6][1] = MFMA_BF16(af2, b2f1, acc_b[6][1], 0, 0, 0);
    acc_a[7][0] = MFMA_BF16(af3, b1f0, acc_a[7][0], 0, 0, 0);
    acc_a[7][1] = MFMA_BF16(af3, b1f1, acc_a[7][1], 0, 0, 0);
    acc_b[7][0] = MFMA_BF16(af3, b2f0, acc_b[7][0], 0, 0, 0);
    acc_b[7][1] = MFMA_BF16(af3, b2f1, acc_b[7][1], 0, 0, 0);
    __builtin_amdgcn_s_setprio(0);
    bc++; if (bc == 3) bc = 0;
  }

  // epilogue: SwiGLU -> bf16 tile (256x128, 64KB) in LDS, coalesced stores
  __syncthreads();
  unsigned short* ht = (unsigned short*)smem;
#pragma unroll
  for (int m = 0; m < 8; m++)
#pragma unroll
    for (int n = 0; n < 2; n++)
#pragma unroll
      for (int r = 0; r < 4; r++) {
        int row = wm * 128 + m * 16 + g * 4 + r;
        int col = wn * 32 + n * 16 + ln;
        float a = acc_a[m][n][r] + s_b1[col];
        float b = acc_b[m][n][r] + s_b2[col];
        float hv = a * (b / (1.f + __expf(-b)));
        ht[row * 128 + col] = f2bf(hv);
      }
  __syncthreads();
#pragma unroll
  for (int q = 0; q < 8; q++) {
    int idx = q * 512 + tid;          // 4096 chunks; 16 per 256B row
    int row = idx >> 4, cc = (idx & 15) * 8;
    short8 v = *(const short8*)(smem + idx * 16);
    *(short8*)(hout + (size_t)(row0 + row) * HDIM + col0 + cc) = v;
  }
}

// ---- GEMM2: BM=256, BN=256, BK=32, 3 bufs, 2-deep counted ------------------
__launch_bounds__(512, 1)
__global__ void k_gemm2(const unsigned short* __restrict__ hin,
                        const unsigned short* __restrict__ wps, const float* __restrict__ bpg,
                        const int* __restrict__ counts, const int* __restrict__ basep,
                        unsigned short* __restrict__ yout) {
  int e = blockIdx.y >> 6;
  int rt = blockIdx.y & 63;
  int cnt = counts[e];
  if (rt >= ((cnt + 255) >> 8)) return;
  int ct = blockIdx.x;              // 0..3 over D (256 cols)
  int row0 = basep[e] + rt * 256;
  int col0 = ct * 256;

  __shared__ char smem[98304];      // 3 bufs x (A 16KB | Bs0 8KB | Bs1 8KB)
  __shared__ float s_bp[256];
  int tid = threadIdx.x;
  if (tid < 256) s_bp[tid] = bpg[e * DDIM + col0 + tid];
  __syncthreads();

  int wave = tid >> 6, l = tid & 63;
  int wm = wave >> 2, wn = wave & 3;          // per wave 128 x 64
  int g = l >> 4, ln = l & 15;

  int c0 = tid, c1 = 512 + tid;
  int r0, kc0, r1, kc1;
  INV_MAP(c0, r0, kc0) INV_MAP(c1, r1, kc1)
  size_t a_src0 = (size_t)(row0 + r0) * 8192 + (size_t)(kc0 * 16);
  size_t a_src1 = (size_t)(row0 + r1) * 8192 + (size_t)(kc1 * 16);
  int a_dst0 = c0 * 16, a_dst1 = c1 * 16;
  const char* b_src0 = (const char*)wps + (size_t)(e * 8 + ct * 2 + 0) * 128 * 8192 + (size_t)tid * 16;
  const char* b_src1 = (const char*)wps + (size_t)(e * 8 + ct * 2 + 1) * 128 * 8192 + (size_t)tid * 16;

  int a_rd[8];
#pragma unroll
  for (int m = 0; m < 8; m++) {
    int r = wm * 128 + m * 16 + ln;
    a_rd[m] = swz(r, g * 16);
  }
  int b_rd[4];
#pragma unroll
  for (int n = 0; n < 4; n++) {
    int ncol = wn * 64 + n * 16 + ln;
    int sub = ncol >> 7, r = ncol & 127;
    b_rd[n] = 16384 + sub * 8192 + swz(r, g * 16);
  }

  f32x4 zero = {0.f, 0.f, 0.f, 0.f};
  f32x4 acc[8][4];
#pragma unroll
  for (int m = 0; m < 8; m++)
#pragma unroll
    for (int n = 0; n < 4; n++) acc[m][n] = zero;

  const char* hb = (const char*)hin;

#pragma unroll
  for (int s = 0; s < 2; s++) {
    char* nb = smem + s * 32768;
    gl_lds16(hb + a_src0 + (size_t)s * 64, nb + a_dst0);
    gl_lds16(b_src0 + (size_t)s * 8192, nb + 16384 + tid * 16);
    gl_lds16(hb + a_src1 + (size_t)s * 64, nb + a_dst1);
    gl_lds16(b_src1 + (size_t)s * 8192, nb + 24576 + tid * 16);
  }

  const int NT = 128;               // K=4096 / 32
  int bc = 0;
  for (int s = 0; s < NT; ++s) {
    if (s < NT - 1) VW4(); else VW0();
    BAR();
    char* buf = smem + bc * 32768;
    int nbi = bc + 2; if (nbi >= 3) nbi -= 3;
    char* nbuf = smem + nbi * 32768;
    bool pf = (s < NT - 2);
    // ---- phase 1: m0-3 x n0-3 ----
    short8 af0, af1, af2, af3, bf0, bf1, bf2, bf3;
    af0 = *(const short8*)(buf + a_rd[0]);
    af1 = *(const short8*)(buf + a_rd[1]);
    af2 = *(const short8*)(buf + a_rd[2]);
    af3 = *(const short8*)(buf + a_rd[3]);
    bf0 = *(const short8*)(buf + b_rd[0]);
    bf1 = *(const short8*)(buf + b_rd[1]);
    bf2 = *(const short8*)(buf + b_rd[2]);
    bf3 = *(const short8*)(buf + b_rd[3]);
    if (pf) {
      gl_lds16(hb + a_src0 + (size_t)(s + 2) * 64, nbuf + a_dst0);
      gl_lds16(b_src0 + (size_t)(s + 2) * 8192, nbuf + 16384 + tid * 16);
    }
    BAR();
    __builtin_amdgcn_s_setprio(1);
    acc[0][0] = MFMA_BF16(af0, bf0, acc[0][0], 0, 0, 0);
    acc[0][1] = MFMA_BF16(af0, bf1, acc[0][1], 0, 0, 0);
    acc[0][2] = MFMA_BF16(af0, bf2, acc[0][2], 0, 0, 0);
    acc[0][3] = MFMA_BF16(af0, bf3, acc[0][3], 0, 0, 0);
    acc[1][0] = MFMA_BF16(af1, bf0, acc[1][0], 0, 0, 0);
    acc[1][1] = MFMA_BF16(af1, bf1, acc[1][1], 0, 0, 0);
    acc[1][2] = MFMA_BF16(af1, bf2, acc[1][2], 0, 0, 0);
    acc[1][3] = MFMA_BF16(af1, bf3, acc[1][3], 0, 0, 0);
    acc[2][0] = MFMA_BF16(af2, bf0, acc[2][0], 0, 0, 0);
    acc[2][1] = MFMA_BF16(af2, bf1, acc[2][1], 0, 0, 0);
    acc[2][2] = MFMA_BF16(af2, bf2, acc[2][2], 0, 0, 0);
    acc[2][3] = MFMA_BF16(af2, bf3, acc[2][3], 0, 0, 0);
    acc[3][0] = MFMA_BF16(af3, bf0, acc[3][0], 0, 0, 0);
    acc[3][1] = MFMA_BF16(af3, bf1, acc[3][1], 0, 0, 0);
    acc[3][2] = MFMA_BF16(af3, bf2, acc[3][2], 0, 0, 0);
    acc[3][3] = MFMA_BF16(af3, bf3, acc[3][3], 0, 0, 0);
    __builtin_amdgcn_s_setprio(0);
    BAR();
    // ---- phase 2: m4-7 x n0-3 (B reused) ----
    af0 = *(const short8*)(buf + a_rd[4]);
    af1 = *(const short8*)(buf + a_rd[5]);
    af2 = *(const short8*)(buf + a_rd[6]);
    af3 = *(const short8*)(buf + a_rd[7]);
    if (pf) {
      gl_lds16(hb + a_src1 + (size_t)(s + 2) * 64, nbuf + a_dst1);
      gl_lds16(b_src1 + (size_t)(s + 2) * 8192, nbuf + 24576 + tid * 16);
    }
    BAR();
    __builtin_amdgcn_s_setprio(1);
    acc[4][0] = MFMA_BF16(af0, bf0, acc[4][0], 0, 0, 0);
    acc[4][1] = MFMA_BF16(af0, bf1, acc[4][1], 0, 0, 0);
    acc[4][2] = MFMA_BF16(af0, bf2, acc[4][2], 0, 0, 0);
    acc[4][3] = MFMA_BF16(af0, bf3, acc[4][3], 0, 0, 0);
    acc[5][0] = MFMA_BF16(af1, bf0, acc[5][0], 0, 0, 0);
    acc[5][1] = MFMA_BF16(af1, bf1, acc[5][1], 0, 0, 0);
    acc[5][2] = MFMA_BF16(af1, bf2, acc[5][2], 0, 0, 0);
    acc[5][3] = MFMA_BF16(af1, bf3, acc[5][3], 0, 0, 0);
    acc[6][0] = MFMA_BF16(af2, bf0, acc[6][0], 0, 0, 0);
    acc[6][1] = MFMA_BF16(af2, bf1, acc[6][1], 0, 0, 0);
    acc[6][2] = MFMA_BF16(af2, bf2, acc[6][2], 0, 0, 0);
    acc[6][3] = MFMA_BF16(af2, bf3, acc[6][3], 0, 0, 0);
    acc[7][0] = MFMA_BF16(af3, bf0, acc[7][0], 0, 0, 0);
    acc[7][1] = MFMA_BF16(af3, bf1, acc[7][1], 0, 0, 0);
    acc[7][2] = MFMA_BF16(af3, bf2, acc[7][2], 0, 0, 0);
    acc[7][3] = MFMA_BF16(af3, bf3, acc[7][3], 0, 0, 0);
    __builtin_amdgcn_s_setprio(0);
    bc++; if (bc == 3) bc = 0;
  }

  // epilogue: two n-half passes through 64KB LDS
  unsigned short* ht = (unsigned short*)smem;
#pragma unroll
  for (int p = 0; p < 2; p++) {
    __syncthreads();
    if ((wn >> 1) == p) {
#pragma unroll
      for (int m = 0; m < 8; m++)
#pragma unroll
        for (int n = 0; n < 4; n++)
#pragma unroll
          for (int r = 0; r < 4; r++) {
            int row = wm * 128 + m * 16 + g * 4 + r;
            int col = wn * 64 + n * 16 + ln;        // global col in [p*128, p*128+128)
            ht[row * 128 + (col - p * 128)] = f2bf(acc[m][n][r] + s_bp[col]);
          }
    }
    __syncthreads();
#pragma unroll
    for (int q = 0; q < 8; q++) {
      int idx = q * 512 + tid;        // 4096 chunks; 16 per 256B row
      int row = idx >> 4, cc = (idx & 15) * 8;
      short8 v = *(const short8*)(smem + idx * 16);
      *(short8*)(yout + (size_t)(row0 + row) * DDIM + col0 + p * 128 + cc) = v;
    }
  }
}

// ---- combine ---------------------------------------------------------------
__global__ void k_combine(const unsigned short* __restrict__ yv,
                          const int* __restrict__ t2r, const float* __restrict__ tkp,
                          float* __restrict__ outp) {
  int gid = blockIdx.x * 256 + threadIdx.x;
  int t = gid >> 8;
  int c4 = (gid & 255) << 2;
  int r0 = t2r[2 * t], r1 = t2r[2 * t + 1];
  float p0 = tkp[2 * t], p1 = tkp[2 * t + 1];
  ushort4v u0 = *(const ushort4v*)(yv + (size_t)r0 * DDIM + c4);
  ushort4v u1 = *(const ushort4v*)(yv + (size_t)r1 * DDIM + c4);
  float4 o;
  o.x = p0 * bf2f(u0.x) + p1 * bf2f(u1.x);
  o.y = p0 * bf2f(u0.y) + p1 * bf2f(u1.y);
  o.z = p0 * bf2f(u0.z) + p1 * bf2f(u1.z);
  o.w = p0 * bf2f(u0.w) + p1 * bf2f(u1.w);
  *(float4*)(outp + (size_t)t * DDIM + c4) = o;
}

extern "C" void kernel_launch(void* const* d_in, const int* in_sizes, int n_in,
                              void* d_out, int out_size, void* d_ws, size_t ws_size,
                              hipStream_t stream) {
  const float* x   = (const float*)d_in[0];
  const float* gw  = (const float*)d_in[1];
  const float* nwt = (const float*)d_in[2];
  const float* noi = (const float*)d_in[3];
  const float* w1  = (const float*)d_in[4];
  const float* b1  = (const float*)d_in[5];
  const float* w2  = (const float*)d_in[6];
  const float* b2  = (const float*)d_in[7];
  const float* wp  = (const float*)d_in[8];
  const float* bp  = (const float*)d_in[9];
  float* outp = (float*)d_out;
  char* ws = (char*)d_ws;

  constexpr size_t SZ_W = (size_t)EEXP * DDIM * HDIM * 2;
  constexpr size_t OFF_XB  = 0;
  constexpr size_t OFF_W1S = OFF_XB + (size_t)T_TOK * DDIM * 2;
  constexpr size_t OFF_W2S = OFF_W1S + SZ_W;
  constexpr size_t OFF_WPS = OFF_W2S + SZ_W;
  constexpr size_t OFF_H   = OFF_WPS + SZ_W;
  constexpr size_t OFF_Y   = OFF_H + (size_t)RMAX * HDIM * 2;
  constexpr size_t OFF_RT  = OFF_Y + (size_t)RMAX * DDIM * 2;
  constexpr size_t OFF_TKI = OFF_RT + (size_t)RMAX * 4;
  constexpr size_t OFF_TKP = OFF_TKI + (size_t)T_TOK * 2 * 4;
  constexpr size_t OFF_T2R = OFF_TKP + (size_t)T_TOK * 2 * 4;
  constexpr size_t OFF_CNT = OFF_T2R + (size_t)T_TOK * 2 * 4;
  constexpr size_t OFF_BAS = OFF_CNT + 256;
  constexpr size_t OFF_CUR = OFF_BAS + 256;
  // total ~407 MB

  unsigned short* xb  = (unsigned short*)(ws + OFF_XB);
  unsigned short* w1s = (unsigned short*)(ws + OFF_W1S);
  unsigned short* w2s = (unsigned short*)(ws + OFF_W2S);
  unsigned short* wps = (unsigned short*)(ws + OFF_WPS);
  unsigned short* h   = (unsigned short*)(ws + OFF_H);
  unsigned short* y   = (unsigned short*)(ws + OFF_Y);
  int*   rowtok = (int*)(ws + OFF_RT);
  int*   tki    = (int*)(ws + OFF_TKI);
  float* tkp    = (float*)(ws + OFF_TKP);
  int*   t2r    = (int*)(ws + OFF_T2R);
  int*   counts = (int*)(ws + OFF_CNT);
  int*   basep  = (int*)(ws + OFF_BAS);
  int*   cursor = (int*)(ws + OFF_CUR);

  dim3 blk(256);
  k_init<<<dim3((RMAX + 255) / 256), blk, 0, stream>>>(rowtok, counts, cursor);
  k_gate<<<dim3(T_TOK / 4), blk, 0, stream>>>(x, gw, nwt, noi, tki, tkp, counts, xb);
  k_convert_all<<<dim3(24576), blk, 0, stream>>>(w1, w2, wp, w1s, w2s, wps);
  k_prefix<<<dim3(1), dim3(64), 0, stream>>>(counts, basep);
  k_scatter<<<dim3(T_TOK / 256), blk, 0, stream>>>(tki, basep, cursor, rowtok, t2r);
  k_gemm1<<<dim3(HDIM / 128, EEXP * 64), dim3(512), 0, stream>>>(xb, w1s, w2s, b1, b2, counts, basep, rowtok, h);
  k_gemm2<<<dim3(DDIM / 256, EEXP * 64), dim3(512), 0, stream>>>(h, wps, bp, counts, basep, y);
  k_combine<<<dim3(T_TOK), blk, 0, stream>>>(y, t2r, tkp, outp);
  (void)in_sizes; (void)n_in; (void)out_size; (void)ws_size;
}

// Round 9
// 922.098 us; speedup vs baseline: 1.1430x; 1.1430x over previous
//
#include <hip/hip_runtime.h>

// MoE: B=4,S=2048,D=1024,E=8,H=4096,K=2.  T = B*S = 8192 tokens.
// R9: revert to R2's proven GEMM structure (128^2 tiles, 256 thr, 3 blk/CU,
// global_load_lds staging, pre-swizzled 16KB weight tiles). Add:
//  - bijective XCD-chunked block swizzle (expert-per-XCD L2 locality)
//  - combine fused into gemm2 epilogue via f32 atomicAdd (out zeroed in init)
//  - all weight converts fused into one launch
// ws usage ~352 MB.

#define T_TOK 8192
#define DDIM 1024
#define EEXP 8
#define HDIM 4096
#define RMAX 17408   // T*K + E*128 padding

typedef short short8 __attribute__((ext_vector_type(8)));
typedef float f32x4 __attribute__((ext_vector_type(4)));
typedef unsigned short ushort4v __attribute__((ext_vector_type(4)));
typedef unsigned int u32;

__device__ __forceinline__ unsigned short f2bf(float f) {
  unsigned u = __builtin_bit_cast(unsigned, f);
  return (unsigned short)((u + 0x7FFFu + ((u >> 16) & 1u)) >> 16);
}
__device__ __forceinline__ void gl_lds16(const void* g, void* l) {
  __builtin_amdgcn_global_load_lds((const u32 __attribute__((address_space(1)))*)g,
                                   (u32 __attribute__((address_space(3)))*)l, 16, 0, 0);
}
#define MFMA_BF16 __builtin_amdgcn_mfma_f32_16x16x32_bf16

// ---- init: zero rowtok/rowp/counts/cursor AND d_out ------------------------
__global__ void k_init(int* __restrict__ rowtok, float* __restrict__ rowp,
                       int* __restrict__ counts, int* __restrict__ cursor,
                       float4* __restrict__ out4) {
  int i = blockIdx.x * 256 + threadIdx.x;      // grid 4096 x 256 -> 1,048,576
  if (i < RMAX) { rowtok[i] = 0; rowp[i] = 0.f; }
  if (i < EEXP) { counts[i] = 0; cursor[i] = 0; }
  float4 z = {0.f, 0.f, 0.f, 0.f};
  out4[i] = z;                                  // 2 * 1,048,576 float4 = 8192*1024 f32
  out4[i + 1048576] = z;
}

// ---- weights: f32 [E][K][N] -> bf16 swizzled 16KB tiles (R2 format), fused -
// Tile = 128 n x 64 k; byte (n*128 + kc*16) ^ ((n&7)<<4) holds B^T[n][kc*8..+7].
__global__ void k_convert_all(const float* __restrict__ w1, const float* __restrict__ w2,
                              const float* __restrict__ wp,
                              unsigned short* __restrict__ w1s, unsigned short* __restrict__ w2s,
                              unsigned short* __restrict__ wps) {
  __shared__ float lbuf[64 * 129];
  int bid = blockIdx.x;                 // 0..12287
  int seg = bid >> 12;                  // 0,1,2
  int t = bid & 4095;
  const float* src; unsigned short* dst; int N, K, ct, kt, e;
  e = t >> 9;
  if (seg == 0)      { src = w1; dst = w1s; N = HDIM; K = DDIM; ct = (t >> 4) & 31; kt = t & 15; }
  else if (seg == 1) { src = w2; dst = w2s; N = HDIM; K = DDIM; ct = (t >> 4) & 31; kt = t & 15; }
  else               { src = wp; dst = wps; N = DDIM; K = HDIM; ct = (t >> 6) & 7;  kt = t & 63; }
  int tid = threadIdx.x;
  const float* s = src + (size_t)e * K * N + (size_t)(kt * 64) * N + ct * 128;
#pragma unroll
  for (int q = 0; q < 8; q++) {
    int idx = q * 256 + tid;
    int row = idx >> 5, c4 = (idx & 31) * 4;
    float4 v = *(const float4*)(s + (size_t)row * N + c4);
    lbuf[row * 129 + c4 + 0] = v.x;
    lbuf[row * 129 + c4 + 1] = v.y;
    lbuf[row * 129 + c4 + 2] = v.z;
    lbuf[row * 129 + c4 + 3] = v.w;
  }
  __syncthreads();
  unsigned short* dt = dst + ((size_t)(e * (N / 128) + ct) * (K / 64) + kt) * 8192;
#pragma unroll
  for (int q = 0; q < 4; q++) {
    int idx = q * 256 + tid;
    int kc = idx & 7, n = idx >> 3;
    short8 o;
#pragma unroll
    for (int j = 0; j < 8; j++) o[j] = (short)f2bf(lbuf[(kc * 8 + j) * 129 + n]);
    int byte = (n * 128 + kc * 16) ^ ((n & 7) << 4);
    *(short8*)((char*)dt + byte) = o;
  }
}

// ---- gating (+ fused x->bf16) ----------------------------------------------
__launch_bounds__(256)
__global__ void k_gate(const float* __restrict__ x, const float* __restrict__ gw,
                       const float* __restrict__ nwt, const float* __restrict__ noi,
                       int* __restrict__ tki, float* __restrict__ tkp,
                       int* __restrict__ counts, unsigned short* __restrict__ xb) {
  __shared__ float gwT[8][1024];
  int tid = threadIdx.x;
#pragma unroll
  for (int q = 0; q < 32; q++) {
    int flat = q * 256 + tid;
    gwT[flat & 7][flat >> 3] = gw[flat];
  }
  __syncthreads();
  int wave = tid >> 6, l = tid & 63;
  int t = blockIdx.x * 4 + wave;
  float acc[8] = {0.f, 0.f, 0.f, 0.f, 0.f, 0.f, 0.f, 0.f};
  const float4* xr = (const float4*)(x + (size_t)t * DDIM);
#pragma unroll
  for (int i = 0; i < 4; i++) {
    float4 xv = xr[l + i * 64];
    int d0 = (l + i * 64) * 4;
    ushort4v o;
    o.x = f2bf(xv.x); o.y = f2bf(xv.y); o.z = f2bf(xv.z); o.w = f2bf(xv.w);
    *(ushort4v*)(xb + (size_t)t * DDIM + d0) = o;
#pragma unroll
    for (int e = 0; e < 8; e++) {
      float4 gv = *(const float4*)&gwT[e][d0];
      acc[e] += xv.x * gv.x + xv.y * gv.y + xv.z * gv.z + xv.w * gv.w;
    }
  }
#pragma unroll
  for (int s = 1; s < 64; s <<= 1) {
#pragma unroll
    for (int e = 0; e < 8; e++) acc[e] += __shfl_xor(acc[e], s, 64);
  }
  if (l == 0) {
    float nl[8];
#pragma unroll
    for (int e = 0; e < 8; e++) nl[e] = acc[e] + noi[t * 8 + e] * nwt[e];
    int i0 = 0; float v0 = nl[0];
#pragma unroll
    for (int e = 1; e < 8; e++) if (nl[e] > v0) { v0 = nl[e]; i0 = e; }
    int i1 = -1; float v1 = -3.4e38f;
#pragma unroll
    for (int e = 0; e < 8; e++) if (e != i0 && nl[e] > v1) { v1 = nl[e]; i1 = e; }
    float ex = __expf(v1 - v0);
    float p0 = 1.f / (1.f + ex);
    float p1 = ex * p0;
    tki[2 * t] = i0; tki[2 * t + 1] = i1;
    tkp[2 * t] = p0; tkp[2 * t + 1] = p1;
    atomicAdd(&counts[i0], 1);
    atomicAdd(&counts[i1], 1);
  }
}

// ---- prefix (pad to 128-row tiles) -----------------------------------------
__global__ void k_prefix(const int* __restrict__ counts, int* __restrict__ basep) {
  if (threadIdx.x == 0) {
    int b = 0;
    for (int e = 0; e < EEXP; e++) { basep[e] = b; b += (counts[e] + 127) & ~127; }
  }
}

// ---- scatter (rowtok + rowp) -----------------------------------------------
__global__ void k_scatter(const int* __restrict__ tki, const float* __restrict__ tkp,
                          const int* __restrict__ basep, int* __restrict__ cursor,
                          int* __restrict__ rowtok, float* __restrict__ rowp) {
  int t = blockIdx.x * 256 + threadIdx.x;
  if (t >= T_TOK) return;
#pragma unroll
  for (int k = 0; k < 2; k++) {
    int e = tki[2 * t + k];
    int pos = atomicAdd(&cursor[e], 1);
    int row = basep[e] + pos;
    rowtok[row] = t;
    rowp[row] = tkp[2 * t + k];
  }
}

// ---- GEMM1 (R2 structure): h = (Xg@w1+b1)*silu(Xg@w2+b2), bf16 out ---------
__launch_bounds__(256, 2)
__global__ void k_gemm1(const unsigned short* __restrict__ xb,
                        const unsigned short* __restrict__ w1s, const unsigned short* __restrict__ w2s,
                        const float* __restrict__ b1g, const float* __restrict__ b2g,
                        const int* __restrict__ counts, const int* __restrict__ basep,
                        const int* __restrict__ rowtok,
                        unsigned short* __restrict__ hout) {
  // XCD-chunked bijective swizzle: grid 16384 = 32 ct x 512 (e*64+rt)
  int lin = blockIdx.x;
  int orig = (lin & 7) * 2048 + (lin >> 3);
  int ct = orig & 31;
  int yy = orig >> 5;
  int e = yy >> 6;
  int rt = yy & 63;
  int cnt = counts[e];
  if (rt >= ((cnt + 127) >> 7)) return;
  int row0 = basep[e] + rt * 128;
  int col0 = ct * 128;

  __shared__ char smem[49152];      // A[128][64] | B1t | B2t (bf16, swizzled)
  __shared__ int s_tok[128];
  __shared__ float s_b1[128], s_b2[128];

  int tid = threadIdx.x;
  if (tid < 128) {
    s_tok[tid] = rowtok[row0 + tid];
    s_b1[tid] = b1g[e * HDIM + col0 + tid];
    s_b2[tid] = b2g[e * HDIM + col0 + tid];
  }
  __syncthreads();

  int wave = tid >> 6, l = tid & 63;
  int wr = (wave >> 1) << 6, wc = (wave & 1) << 6;
  int g = l >> 4, ln = l & 15;

  int sr[4], stok[4], sxor[4];
#pragma unroll
  for (int q = 0; q < 4; q++) {
    int flat = q * 256 + tid;
    sr[q] = flat;
    int r = flat >> 3, c = flat & 7;
    stok[q] = s_tok[r];
    sxor[q] = (c ^ (r & 7)) << 3;
  }

  f32x4 zero = {0.f, 0.f, 0.f, 0.f};
  f32x4 acc_a[4][4], acc_b[4][4];
#pragma unroll
  for (int m = 0; m < 4; m++)
#pragma unroll
    for (int n = 0; n < 4; n++) { acc_a[m][n] = zero; acc_b[m][n] = zero; }

  const unsigned short* w1t = w1s + ((size_t)(e * 32 + ct) * 16) * 8192;
  const unsigned short* w2t = w2s + ((size_t)(e * 32 + ct) * 16) * 8192;

  for (int kt = 0; kt < 16; kt++) {
#pragma unroll
    for (int q = 0; q < 4; q++) {
      gl_lds16(xb + (size_t)stok[q] * DDIM + kt * 64 + sxor[q], smem + sr[q] * 16);
      gl_lds16(w1t + (size_t)kt * 8192 + sr[q] * 8, smem + 16384 + sr[q] * 16);
      gl_lds16(w2t + (size_t)kt * 8192 + sr[q] * 8, smem + 32768 + sr[q] * 16);
    }
    __syncthreads();
#pragma unroll
    for (int ks = 0; ks < 2; ks++) {
      int kb = ks * 64 + g * 16;
      short8 af[4], bf1[4], bf2[4];
#pragma unroll
      for (int m = 0; m < 4; m++) {
        int r = wr + m * 16 + ln;
        af[m] = *(const short8*)(smem + ((r * 128 + kb) ^ ((r & 7) << 4)));
      }
#pragma unroll
      for (int n = 0; n < 4; n++) {
        int r = wc + n * 16 + ln;
        int byte = (r * 128 + kb) ^ ((r & 7) << 4);
        bf1[n] = *(const short8*)(smem + 16384 + byte);
        bf2[n] = *(const short8*)(smem + 32768 + byte);
      }
#pragma unroll
      for (int m = 0; m < 4; m++)
#pragma unroll
        for (int n = 0; n < 4; n++) {
          acc_a[m][n] = MFMA_BF16(af[m], bf1[n], acc_a[m][n], 0, 0, 0);
          acc_b[m][n] = MFMA_BF16(af[m], bf2[n], acc_b[m][n], 0, 0, 0);
        }
    }
    __syncthreads();
  }
  // epilogue: SwiGLU -> bf16 tile in LDS, then coalesced stores
  unsigned short* ht = (unsigned short*)smem;
#pragma unroll
  for (int m = 0; m < 4; m++)
#pragma unroll
    for (int n = 0; n < 4; n++)
#pragma unroll
      for (int r = 0; r < 4; r++) {
        int row = wr + m * 16 + g * 4 + r;
        int col = wc + n * 16 + ln;
        float a = acc_a[m][n][r] + s_b1[col];
        float b = acc_b[m][n][r] + s_b2[col];
        float hv = a * (b / (1.f + __expf(-b)));
        ht[row * 128 + col] = f2bf(hv);
      }
  __syncthreads();
#pragma unroll
  for (int q = 0; q < 8; q++) {
    int idx = q * 256 + tid;
    int row = idx >> 4, chunk = idx & 15;
    short8 v = *(const short8*)(smem + idx * 16);
    *(short8*)(hout + (size_t)(row0 + row) * HDIM + col0 + chunk * 8) = v;
  }
}

// ---- GEMM2 (R2 structure) + fused weighted combine via atomicAdd -----------
__launch_bounds__(256, 2)
__global__ void k_gemm2(const unsigned short* __restrict__ hin,
                        const unsigned short* __restrict__ wps, const float* __restrict__ bpg,
                        const int* __restrict__ counts, const int* __restrict__ basep,
                        const int* __restrict__ rowtok, const float* __restrict__ rowp,
                        float* __restrict__ outp) {
  // XCD-chunked bijective swizzle: grid 4096 = 8 ct x 512 (e*64+rt)
  int lin = blockIdx.x;
  int orig = (lin & 7) * 512 + (lin >> 3);
  int ct = orig & 7;
  int yy = orig >> 3;
  int e = yy >> 6;
  int rt = yy & 63;
  int cnt = counts[e];
  if (rt >= ((cnt + 127) >> 7)) return;
  int row0 = basep[e] + rt * 128;
  int col0 = ct * 128;

  __shared__ char smem[32768];      // A[128][64] | Bt
  __shared__ int s_tok[128];
  __shared__ float s_p[128], s_bp[128];
  int tid = threadIdx.x;
  if (tid < 128) {
    s_tok[tid] = rowtok[row0 + tid];
    s_p[tid] = rowp[row0 + tid];
    s_bp[tid] = bpg[e * DDIM + col0 + tid];
  }
  __syncthreads();

  int wave = tid >> 6, l = tid & 63;
  int wr = (wave >> 1) << 6, wc = (wave & 1) << 6;
  int g = l >> 4, ln = l & 15;

  int sr[4], srow[4], sxor[4];
#pragma unroll
  for (int q = 0; q < 4; q++) {
    int flat = q * 256 + tid;
    sr[q] = flat;
    int r = flat >> 3, c = flat & 7;
    srow[q] = row0 + r;
    sxor[q] = (c ^ (r & 7)) << 3;
  }

  f32x4 zero = {0.f, 0.f, 0.f, 0.f};
  f32x4 acc[4][4];
#pragma unroll
  for (int m = 0; m < 4; m++)
#pragma unroll
    for (int n = 0; n < 4; n++) acc[m][n] = zero;

  const unsigned short* wpt = wps + ((size_t)(e * 8 + ct) * 64) * 8192;

  for (int kt = 0; kt < 64; kt++) {
#pragma unroll
    for (int q = 0; q < 4; q++) {
      gl_lds16(hin + (size_t)srow[q] * HDIM + kt * 64 + sxor[q], smem + sr[q] * 16);
      gl_lds16(wpt + (size_t)kt * 8192 + sr[q] * 8, smem + 16384 + sr[q] * 16);
    }
    __syncthreads();
#pragma unroll
    for (int ks = 0; ks < 2; ks++) {
      int kb = ks * 64 + g * 16;
      short8 af[4], bf[4];
#pragma unroll
      for (int m = 0; m < 4; m++) {
        int r = wr + m * 16 + ln;
        af[m] = *(const short8*)(smem + ((r * 128 + kb) ^ ((r & 7) << 4)));
      }
#pragma unroll
      for (int n = 0; n < 4; n++) {
        int r = wc + n * 16 + ln;
        bf[n] = *(const short8*)(smem + 16384 + ((r * 128 + kb) ^ ((r & 7) << 4)));
      }
#pragma unroll
      for (int m = 0; m < 4; m++)
#pragma unroll
        for (int n = 0; n < 4; n++)
          acc[m][n] = MFMA_BF16(af[m], bf[n], acc[m][n], 0, 0, 0);
    }
    __syncthreads();
  }

  // fused combine: out[tok, col] += p * (acc + bp)   (pad rows have p == 0)
#pragma unroll
  for (int m = 0; m < 4; m++)
#pragma unroll
    for (int r = 0; r < 4; r++) {
      int row = wr + m * 16 + g * 4 + r;
      float p = s_p[row];
      if (p != 0.f) {
        size_t obase = (size_t)s_tok[row] * DDIM + col0;
#pragma unroll
        for (int n = 0; n < 4; n++) {
          int col = wc + n * 16 + ln;
          atomicAdd(&outp[obase + col], p * (acc[m][n][r] + s_bp[col]));
        }
      }
    }
}

extern "C" void kernel_launch(void* const* d_in, const int* in_sizes, int n_in,
                              void* d_out, int out_size, void* d_ws, size_t ws_size,
                              hipStream_t stream) {
  const float* x   = (const float*)d_in[0];
  const float* gw  = (const float*)d_in[1];
  const float* nwt = (const float*)d_in[2];
  const float* noi = (const float*)d_in[3];
  const float* w1  = (const float*)d_in[4];
  const float* b1  = (const float*)d_in[5];
  const float* w2  = (const float*)d_in[6];
  const float* b2  = (const float*)d_in[7];
  const float* wp  = (const float*)d_in[8];
  const float* bp  = (const float*)d_in[9];
  float* outp = (float*)d_out;
  char* ws = (char*)d_ws;

  constexpr size_t SZ_W = (size_t)EEXP * DDIM * HDIM * 2;          // 64 MB each
  constexpr size_t OFF_XB  = 0;
  constexpr size_t OFF_W1S = OFF_XB + (size_t)T_TOK * DDIM * 2;    // 16.8 MB
  constexpr size_t OFF_W2S = OFF_W1S + SZ_W;
  constexpr size_t OFF_WPS = OFF_W2S + SZ_W;
  constexpr size_t OFF_H   = OFF_WPS + SZ_W;
  constexpr size_t OFF_RT  = OFF_H + (size_t)RMAX * HDIM * 2;      // 142.6 MB
  constexpr size_t OFF_RP  = OFF_RT + (size_t)RMAX * 4;
  constexpr size_t OFF_TKI = OFF_RP + (size_t)RMAX * 4;
  constexpr size_t OFF_TKP = OFF_TKI + (size_t)T_TOK * 2 * 4;
  constexpr size_t OFF_CNT = OFF_TKP + (size_t)T_TOK * 2 * 4;
  constexpr size_t OFF_BAS = OFF_CNT + 256;
  constexpr size_t OFF_CUR = OFF_BAS + 256;
  // total ~352 MB

  unsigned short* xb  = (unsigned short*)(ws + OFF_XB);
  unsigned short* w1s = (unsigned short*)(ws + OFF_W1S);
  unsigned short* w2s = (unsigned short*)(ws + OFF_W2S);
  unsigned short* wps = (unsigned short*)(ws + OFF_WPS);
  unsigned short* h   = (unsigned short*)(ws + OFF_H);
  int*   rowtok = (int*)(ws + OFF_RT);
  float* rowp   = (float*)(ws + OFF_RP);
  int*   tki    = (int*)(ws + OFF_TKI);
  float* tkp    = (float*)(ws + OFF_TKP);
  int*   counts = (int*)(ws + OFF_CNT);
  int*   basep  = (int*)(ws + OFF_BAS);
  int*   cursor = (int*)(ws + OFF_CUR);

  dim3 blk(256);
  k_init<<<dim3(4096), blk, 0, stream>>>(rowtok, rowp, counts, cursor, (float4*)outp);
  k_gate<<<dim3(T_TOK / 4), blk, 0, stream>>>(x, gw, nwt, noi, tki, tkp, counts, xb);
  k_convert_all<<<dim3(12288), blk, 0, stream>>>(w1, w2, wp, w1s, w2s, wps);
  k_prefix<<<dim3(1), dim3(64), 0, stream>>>(counts, basep);
  k_scatter<<<dim3(T_TOK / 256), blk, 0, stream>>>(tki, tkp, basep, cursor, rowtok, rowp);
  k_gemm1<<<dim3(16384), blk, 0, stream>>>(xb, w1s, w2s, b1, b2, counts, basep, rowtok, h);
  k_gemm2<<<dim3(4096), blk, 0, stream>>>(h, wps, bp, counts, basep, rowtok, rowp, outp);
  (void)in_sizes; (void)n_in; (void)out_size; (void)ws_size;
}